// Round 1
// baseline (1272.446 us; speedup 1.0000x reference)
//
#include <hip/hip_runtime.h>
#include <stdint.h>

#define TOK   4096
#define DIM   1024
#define NH    16
#define DHD   64
#define NE    8
#define HIDN  2048
#define BATCH 2
#define SEQ   2048

using floatx4 = __attribute__((ext_vector_type(4))) float;
using bfx8    = __attribute__((ext_vector_type(8))) __bf16;
using shortx8 = __attribute__((ext_vector_type(8))) short;

__device__ __forceinline__ unsigned short f2bf(float f) {
    union { float f; unsigned u; } v; v.f = f;
    unsigned u = v.u;
    u += 0x7fffu + ((u >> 16) & 1u);
    return (unsigned short)(u >> 16);
}

__device__ __forceinline__ floatx4 mfma16(bfx8 a, bfx8 b, floatx4 c) {
    return __builtin_amdgcn_mfma_f32_16x16x32_bf16(a, b, c, 0, 0, 0);
}

// ---------------- elementwise f32 -> bf16 convert ----------------
__global__ __launch_bounds__(256) void cvt_kernel(const float* __restrict__ in,
                                                  unsigned short* __restrict__ out, int n) {
    int i = (blockIdx.x * 256 + threadIdx.x) * 4;
    if (i < n) {
        float4 v = *reinterpret_cast<const float4*>(in + i);
        out[i + 0] = f2bf(v.x);
        out[i + 1] = f2bf(v.y);
        out[i + 2] = f2bf(v.z);
        out[i + 3] = f2bf(v.w);
    }
}

// ---------------- layernorm: one block per row ----------------
__global__ __launch_bounds__(256) void ln_kernel(const float* __restrict__ x,
                                                 const float* __restrict__ g,
                                                 const float* __restrict__ b,
                                                 unsigned short* __restrict__ obf,
                                                 float* __restrict__ of32) {
    int t = blockIdx.x;
    int tid = threadIdx.x;
    const float* xr = x + (size_t)t * DIM;
    float4 v = *reinterpret_cast<const float4*>(xr + tid * 4);
    float s  = v.x + v.y + v.z + v.w;
    float s2 = v.x * v.x + v.y * v.y + v.z * v.z + v.w * v.w;
    for (int o = 32; o > 0; o >>= 1) {
        s  += __shfl_down(s,  o, 64);
        s2 += __shfl_down(s2, o, 64);
    }
    __shared__ float red[10];
    int lane = tid & 63, w = tid >> 6;
    if (lane == 0) { red[w] = s; red[4 + w] = s2; }
    __syncthreads();
    if (tid == 0) {
        float ts = red[0] + red[1] + red[2] + red[3];
        float t2 = red[4] + red[5] + red[6] + red[7];
        float mu = ts * (1.0f / DIM);
        float var = t2 * (1.0f / DIM) - mu * mu;
        red[8] = mu;
        red[9] = rsqrtf(var + 1e-5f);
    }
    __syncthreads();
    float mu = red[8], rstd = red[9];
    float4 gv = *reinterpret_cast<const float4*>(g + tid * 4);
    float4 bv = *reinterpret_cast<const float4*>(b + tid * 4);
    float y0 = (v.x - mu) * rstd * gv.x + bv.x;
    float y1 = (v.y - mu) * rstd * gv.y + bv.y;
    float y2 = (v.z - mu) * rstd * gv.z + bv.z;
    float y3 = (v.w - mu) * rstd * gv.w + bv.w;
    size_t o = (size_t)t * DIM + tid * 4;
    obf[o + 0] = f2bf(y0);
    obf[o + 1] = f2bf(y1);
    obf[o + 2] = f2bf(y2);
    obf[o + 3] = f2bf(y3);
    if (of32) {
        of32[o + 0] = y0; of32[o + 1] = y1; of32[o + 2] = y2; of32[o + 3] = y3;
    }
}

// ---------------- generic MFMA GEMM: C = A(bf16 [M][K]) * B^T (+ epilogue) ----------------
// EPI: 0 = bias -> bf16 ; 1 = bias + resid -> f32 ; 2 = bias + gelu -> bf16 (row go+r)
//      3 = bias -> f32 (row go+r)
// BF32KN: B is f32 [K][N] (per-expert stride K*N), staged with transpose+convert.
//         else B is bf16 [N][K].
// GATHER: A rows indirect through gtok[go+row]; else if cnt: A row = go+row; else row.
template <int EPI, bool BF32KN, bool GATHER>
__global__ __launch_bounds__(256) void gemm_kernel(const unsigned short* __restrict__ A,
                                                   const void* __restrict__ B,
                                                   void* __restrict__ C,
                                                   const float* __restrict__ bias,
                                                   const float* __restrict__ resid,
                                                   const int* __restrict__ cnt,
                                                   const int* __restrict__ goff,
                                                   const int* __restrict__ gtok,
                                                   int M, int N, int K) {
    int e = blockIdx.z;
    int Me = cnt ? cnt[e] : M;
    int brow = blockIdx.y * 128;
    if (brow >= Me) return;
    int bcol = blockIdx.x * 128;
    int go = goff ? goff[e] : 0;
    const float* biasp = bias + (size_t)e * N;

    __shared__ short As[128][40];
    __shared__ short Bs[128][40];

    int tid = threadIdx.x;
    int lane = tid & 63, w = tid >> 6;
    int wr = w >> 1, wc = w & 1;
    int cg = lane >> 4, cl = lane & 15;

    floatx4 acc[4][4];
    for (int m = 0; m < 4; m++)
        for (int n = 0; n < 4; n++) acc[m][n] = (floatx4){0.f, 0.f, 0.f, 0.f};

    int arow_l = tid >> 1, ahalf = tid & 1;
    int gr = brow + arow_l;
    bool avalid = gr < Me;
    long asrc = 0;
    if (avalid) {
        if (GATHER) asrc = gtok[go + gr];
        else if (cnt) asrc = go + gr;
        else asrc = gr;
    }

    for (int kt = 0; kt < K; kt += 32) {
        { // stage A (bf16 [M][K], linear rows of 32 k)
            const unsigned short* ap = A + asrc * (long)K + kt + ahalf * 16;
            shortx8 v0 = {0, 0, 0, 0, 0, 0, 0, 0}, v1 = v0;
            if (avalid) {
                v0 = *reinterpret_cast<const shortx8*>(ap);
                v1 = *reinterpret_cast<const shortx8*>(ap + 8);
            }
            *reinterpret_cast<shortx8*>(&As[arow_l][ahalf * 16]) = v0;
            *reinterpret_cast<shortx8*>(&As[arow_l][ahalf * 16 + 8]) = v1;
        }
        if (!BF32KN) { // B bf16 [N][K]
            const unsigned short* bp =
                (const unsigned short*)B + (size_t)(bcol + arow_l) * K + kt + ahalf * 16;
            *reinterpret_cast<shortx8*>(&Bs[arow_l][ahalf * 16]) =
                *reinterpret_cast<const shortx8*>(bp);
            *reinterpret_cast<shortx8*>(&Bs[arow_l][ahalf * 16 + 8]) =
                *reinterpret_cast<const shortx8*>(bp + 8);
        } else { // B f32 [K][N] -> transpose-convert into Bs[n][k]
            const float* bp0 = (const float*)B + (size_t)e * K * N;
            for (int p = 0; p < 2; p++) {
                int k  = p * 16 + (tid >> 4);
                int n0 = (tid & 15) * 8;
                const float* bp = bp0 + (size_t)(kt + k) * N + bcol + n0;
                float4 f0 = *reinterpret_cast<const float4*>(bp);
                float4 f1 = *reinterpret_cast<const float4*>(bp + 4);
                Bs[n0 + 0][k] = (short)f2bf(f0.x);
                Bs[n0 + 1][k] = (short)f2bf(f0.y);
                Bs[n0 + 2][k] = (short)f2bf(f0.z);
                Bs[n0 + 3][k] = (short)f2bf(f0.w);
                Bs[n0 + 4][k] = (short)f2bf(f1.x);
                Bs[n0 + 5][k] = (short)f2bf(f1.y);
                Bs[n0 + 6][k] = (short)f2bf(f1.z);
                Bs[n0 + 7][k] = (short)f2bf(f1.w);
            }
        }
        __syncthreads();
        bfx8 af[4], bfr[4];
        for (int m = 0; m < 4; m++)
            af[m] = *reinterpret_cast<const bfx8*>(&As[wr * 64 + m * 16 + cl][cg * 8]);
        for (int n = 0; n < 4; n++)
            bfr[n] = *reinterpret_cast<const bfx8*>(&Bs[wc * 64 + n * 16 + cl][cg * 8]);
        for (int m = 0; m < 4; m++)
            for (int n = 0; n < 4; n++) acc[m][n] = mfma16(af[m], bfr[n], acc[m][n]);
        __syncthreads();
    }

    for (int m = 0; m < 4; m++) {
        for (int j = 0; j < 4; j++) {
            int r = brow + wr * 64 + m * 16 + cg * 4 + j;
            if (r >= Me) continue;
            for (int n = 0; n < 4; n++) {
                int col = bcol + wc * 64 + n * 16 + cl;
                float v = acc[m][n][j] + biasp[col];
                if (EPI == 0) {
                    ((unsigned short*)C)[(size_t)r * N + col] = f2bf(v);
                } else if (EPI == 1) {
                    size_t o = (size_t)r * N + col;
                    ((float*)C)[o] = v + resid[o];
                } else if (EPI == 2) {
                    float gg = 0.5f * v * (1.0f + erff(v * 0.70710678f));
                    ((unsigned short*)C)[(size_t)(go + r) * N + col] = f2bf(gg);
                } else {
                    ((float*)C)[(size_t)(go + r) * N + col] = v;
                }
            }
        }
    }
}

// ---------------- flash attention ----------------
// grid (SEQ/64, NH, BATCH), 256 threads = 4 waves, each wave owns 16 q rows.
__global__ __launch_bounds__(256) void attn_kernel(const unsigned short* __restrict__ qkv,
                                                   const unsigned char* __restrict__ mask,
                                                   unsigned short* __restrict__ ao) {
    __shared__ short Ks[32][72];      // K tile, pad -> 144B rows (16B aligned)
    __shared__ short Vt[64][40];      // V^T tile, 80B rows
    __shared__ short Ps[4][16][40];   // per-wave P buffer

    int tid = threadIdx.x, lane = tid & 63, w = tid >> 6;
    int cg = lane >> 4, cl = lane & 15;
    int qb = blockIdx.x * 64, h = blockIdx.y, b = blockIdx.z;

    int tq = qb + w * 16 + cl;
    const unsigned short* qrow = qkv + (size_t)(b * SEQ + tq) * 3 * DIM + h * DHD;
    bfx8 aq0 = *reinterpret_cast<const bfx8*>(qrow + cg * 8);
    bfx8 aq1 = *reinterpret_cast<const bfx8*>(qrow + 32 + cg * 8);

    floatx4 accO[4];
    for (int d = 0; d < 4; d++) accO[d] = (floatx4){0.f, 0.f, 0.f, 0.f};
    float m0[4], l0[4];
    for (int j = 0; j < 4; j++) { m0[j] = -3.0e38f; l0[j] = 0.f; }

    for (int kt = 0; kt < SEQ; kt += 32) {
        { // stage K and V^T
            int r = tid >> 3, c8 = (tid & 7) * 8;
            const unsigned short* trow = qkv + (size_t)(b * SEQ + kt + r) * 3 * DIM + h * DHD;
            shortx8 kvv = *reinterpret_cast<const shortx8*>(trow + DIM + c8);
            *reinterpret_cast<shortx8*>(&Ks[r][c8]) = kvv;
            shortx8 vv = *reinterpret_cast<const shortx8*>(trow + 2 * DIM + c8);
            for (int e2 = 0; e2 < 8; e2++) Vt[c8 + e2][r] = vv[e2];
        }
        __syncthreads();

        floatx4 accS[2];
        accS[0] = (floatx4){0.f, 0.f, 0.f, 0.f};
        accS[1] = (floatx4){0.f, 0.f, 0.f, 0.f};
        for (int nt = 0; nt < 2; nt++) {
            bfx8 bk0 = *reinterpret_cast<const bfx8*>(&Ks[nt * 16 + cl][cg * 8]);
            bfx8 bk1 = *reinterpret_cast<const bfx8*>(&Ks[nt * 16 + cl][32 + cg * 8]);
            accS[nt] = mfma16(aq0, bk0, accS[nt]);
            accS[nt] = mfma16(aq1, bk1, accS[nt]);
        }

        float mk0 = mask[b * SEQ + kt + cl]      ? -1e9f : 0.f;
        float mk1 = mask[b * SEQ + kt + 16 + cl] ? -1e9f : 0.f;
        float s0[4], s1[4], pm[4];
        for (int j = 0; j < 4; j++) {
            s0[j] = accS[0][j] * 0.125f + mk0;
            s1[j] = accS[1][j] * 0.125f + mk1;
            pm[j] = fmaxf(s0[j], s1[j]);
        }
        for (int o = 1; o < 16; o <<= 1)
            for (int j = 0; j < 4; j++) pm[j] = fmaxf(pm[j], __shfl_xor(pm[j], o, 16));
        float al[4], rs[4];
        for (int j = 0; j < 4; j++) {
            float mn = fmaxf(m0[j], pm[j]);
            al[j] = __expf(m0[j] - mn);
            m0[j] = mn;
            s0[j] = __expf(s0[j] - mn);
            s1[j] = __expf(s1[j] - mn);
            rs[j] = s0[j] + s1[j];
        }
        for (int o = 1; o < 16; o <<= 1)
            for (int j = 0; j < 4; j++) rs[j] += __shfl_xor(rs[j], o, 16);
        for (int j = 0; j < 4; j++) l0[j] = l0[j] * al[j] + rs[j];
        for (int d = 0; d < 4; d++)
            for (int j = 0; j < 4; j++) accO[d][j] *= al[j];

        for (int j = 0; j < 4; j++) {
            Ps[w][cg * 4 + j][cl]      = (short)f2bf(s0[j]);
            Ps[w][cg * 4 + j][16 + cl] = (short)f2bf(s1[j]);
        }
        // same-wave LDS RAW: compiler inserts lgkmcnt wait (plain HIP, no inline asm)
        bfx8 pa = *reinterpret_cast<const bfx8*>(&Ps[w][cl][cg * 8]);
        for (int d = 0; d < 4; d++) {
            bfx8 bv = *reinterpret_cast<const bfx8*>(&Vt[d * 16 + cl][cg * 8]);
            accO[d] = mfma16(pa, bv, accO[d]);
        }
        __syncthreads();
    }

    for (int d = 0; d < 4; d++)
        for (int j = 0; j < 4; j++) {
            size_t row = (size_t)(b * SEQ + qb + w * 16 + cg * 4 + j);
            ao[row * DIM + h * DHD + d * 16 + cl] = f2bf(accO[d][j] / l0[j]);
        }
}

// ---------------- gating: one wave per token ----------------
__global__ __launch_bounds__(256) void gate_kernel(const float* __restrict__ xn2,
                                                   const float* __restrict__ Wg,
                                                   const float* __restrict__ bg,
                                                   int* __restrict__ idx,
                                                   float* __restrict__ wts,
                                                   int* __restrict__ cnt,
                                                   float* __restrict__ me_sum) {
    __shared__ float bme[8];
    if (threadIdx.x < 8) bme[threadIdx.x] = 0.f;
    __syncthreads();
    int w = threadIdx.x >> 6, lane = threadIdx.x & 63;
    int t = blockIdx.x * 4 + w;
    float acc[8];
    for (int e = 0; e < 8; e++) acc[e] = 0.f;
    const float* xr = xn2 + (size_t)t * DIM;
    for (int d = lane; d < DIM; d += 64) {
        float xv = xr[d];
        const float* wr = Wg + d * 8;
        for (int e = 0; e < 8; e++) acc[e] += xv * wr[e];
    }
    for (int o = 32; o > 0; o >>= 1)
        for (int e = 0; e < 8; e++) acc[e] += __shfl_xor(acc[e], o, 64);
    if (lane == 0) {
        float p[8];
        float mx = -3e38f;
        for (int e = 0; e < 8; e++) { acc[e] += bg[e]; mx = fmaxf(mx, acc[e]); }
        float se = 0.f;
        for (int e = 0; e < 8; e++) { p[e] = expf(acc[e] - mx); se += p[e]; }
        for (int e = 0; e < 8; e++) p[e] /= se;
        int i0 = 0; float v0 = p[0];
        for (int e = 1; e < 8; e++) if (p[e] > v0) { v0 = p[e]; i0 = e; }
        int i1 = -1; float v1 = -3e38f;
        for (int e = 0; e < 8; e++) if (e != i0 && p[e] > v1) { v1 = p[e]; i1 = e; }
        float sw = v0 + v1;
        idx[t * 2]     = i0;
        idx[t * 2 + 1] = i1;
        wts[t * 2]     = v0 / sw;
        wts[t * 2 + 1] = v1 / sw;
        atomicAdd(&cnt[i0], 1);
        atomicAdd(&cnt[i1], 1);
        for (int e = 0; e < 8; e++) atomicAdd(&bme[e], p[e]);
    }
    __syncthreads();
    if (threadIdx.x < 8) atomicAdd(&me_sum[threadIdx.x], bme[threadIdx.x]);
}

__global__ void prefix_kernel(const int* __restrict__ cnt, int* __restrict__ goff) {
    if (threadIdx.x == 0) {
        int s = 0;
        for (int e = 0; e < 8; e++) { goff[e] = s; s += cnt[e]; }
        goff[8] = s;
    }
}

__global__ __launch_bounds__(256) void assign_kernel(const int* __restrict__ idx,
                                                     const int* __restrict__ goff,
                                                     int* __restrict__ fill,
                                                     int* __restrict__ gtok,
                                                     int* __restrict__ tpos) {
    int t = blockIdx.x * 256 + threadIdx.x;
    for (int j = 0; j < 2; j++) {
        int e = idx[t * 2 + j];
        int pos = goff[e] + atomicAdd(&fill[e], 1);
        gtok[pos] = t;
        tpos[t * 2 + j] = pos;
    }
}

__global__ __launch_bounds__(256) void combine_kernel(const float* __restrict__ x2,
                                                      const float* __restrict__ eo,
                                                      const float* __restrict__ wts,
                                                      const int* __restrict__ tpos,
                                                      float* __restrict__ out) {
    int t = blockIdx.x;
    int c = threadIdx.x * 4;
    float w0 = wts[t * 2], w1 = wts[t * 2 + 1];
    int p0 = tpos[t * 2], p1 = tpos[t * 2 + 1];
    float4 r  = *reinterpret_cast<const float4*>(x2 + (size_t)t * DIM + c);
    float4 a  = *reinterpret_cast<const float4*>(eo + (size_t)p0 * DIM + c);
    float4 bb = *reinterpret_cast<const float4*>(eo + (size_t)p1 * DIM + c);
    float4 o;
    o.x = r.x + w0 * a.x + w1 * bb.x;
    o.y = r.y + w0 * a.y + w1 * bb.y;
    o.z = r.z + w0 * a.z + w1 * bb.z;
    o.w = r.w + w0 * a.w + w1 * bb.w;
    *reinterpret_cast<float4*>(out + (size_t)t * DIM + c) = o;
}

__global__ void loss_kernel(const float* __restrict__ me_sum, const int* __restrict__ cnt,
                            float* __restrict__ out) {
    if (threadIdx.x == 0 && blockIdx.x == 0) {
        float s = 0.f;
        for (int e = 0; e < 8; e++)
            s += (me_sum[e] / 4096.0f) * ((float)cnt[e] / 4096.0f);
        out[(size_t)TOK * DIM] = 8.0f * s;
    }
}

extern "C" void kernel_launch(void* const* d_in, const int* in_sizes, int n_in,
                              void* d_out, int out_size, void* d_ws, size_t ws_size,
                              hipStream_t stream) {
    const float* x    = (const float*)d_in[0];
    const unsigned char* mask = (const unsigned char*)d_in[1];
    const float* ln1g = (const float*)d_in[2];
    const float* ln1b = (const float*)d_in[3];
    const float* Wqkv = (const float*)d_in[4];
    const float* bqkv = (const float*)d_in[5];
    const float* Wo   = (const float*)d_in[6];
    const float* bo   = (const float*)d_in[7];
    const float* ln2g = (const float*)d_in[8];
    const float* ln2b = (const float*)d_in[9];
    const float* Wg   = (const float*)d_in[10];
    const float* bg   = (const float*)d_in[11];
    const float* W1   = (const float*)d_in[12];
    const float* b1   = (const float*)d_in[13];
    const float* W2   = (const float*)d_in[14];
    const float* b2   = (const float*)d_in[15];
    float* out = (float*)d_out;

    char* ws = (char*)d_ws;
    int*   cnt  = (int*)(ws + 0);
    int*   fill = (int*)(ws + 64);
    int*   goff = (int*)(ws + 128);
    float* me   = (float*)(ws + 192);
    size_t off = 1024;
    auto alloc = [&](size_t bytes) -> void* {
        void* p = ws + off;
        off += (bytes + 255) & ~(size_t)255;
        return p;
    };
    unsigned short* xn1   = (unsigned short*)alloc((size_t)TOK * DIM * 2);
    unsigned short* qkvb  = (unsigned short*)alloc((size_t)TOK * 3 * DIM * 2);
    unsigned short* aob   = (unsigned short*)alloc((size_t)TOK * DIM * 2);
    float*          x2    = (float*)alloc((size_t)TOK * DIM * 4);
    float*          xn2f  = (float*)alloc((size_t)TOK * DIM * 4);
    unsigned short* xn2b  = (unsigned short*)alloc((size_t)TOK * DIM * 2);
    unsigned short* hb    = (unsigned short*)alloc((size_t)2 * TOK * HIDN * 2);
    float*          eof   = (float*)alloc((size_t)2 * TOK * DIM * 4);
    unsigned short* wqkvb = (unsigned short*)alloc((size_t)3 * DIM * DIM * 2);
    unsigned short* wob   = (unsigned short*)alloc((size_t)DIM * DIM * 2);
    int*            idxp  = (int*)alloc((size_t)TOK * 2 * 4);
    float*          wtsp  = (float*)alloc((size_t)TOK * 2 * 4);
    int*            gtok  = (int*)alloc((size_t)2 * TOK * 4);
    int*            tpos  = (int*)alloc((size_t)TOK * 2 * 4);

    hipMemsetAsync(ws, 0, 256, stream);

    cvt_kernel<<<3 * DIM * DIM / 1024, 256, 0, stream>>>(Wqkv, wqkvb, 3 * DIM * DIM);
    cvt_kernel<<<DIM * DIM / 1024, 256, 0, stream>>>(Wo, wob, DIM * DIM);

    ln_kernel<<<TOK, 256, 0, stream>>>(x, ln1g, ln1b, xn1, nullptr);

    gemm_kernel<0, false, false><<<dim3(24, 32, 1), 256, 0, stream>>>(
        xn1, wqkvb, qkvb, bqkv, nullptr, nullptr, nullptr, nullptr, TOK, 3 * DIM, DIM);

    attn_kernel<<<dim3(SEQ / 64, NH, BATCH), 256, 0, stream>>>(qkvb, mask, aob);

    gemm_kernel<1, false, false><<<dim3(8, 32, 1), 256, 0, stream>>>(
        aob, wob, x2, bo, x, nullptr, nullptr, nullptr, TOK, DIM, DIM);

    ln_kernel<<<TOK, 256, 0, stream>>>(x2, ln2g, ln2b, xn2b, xn2f);

    gate_kernel<<<TOK / 4, 256, 0, stream>>>(xn2f, Wg, bg, idxp, wtsp, cnt, me);
    prefix_kernel<<<1, 64, 0, stream>>>(cnt, goff);
    assign_kernel<<<TOK / 256, 256, 0, stream>>>(idxp, goff, fill, gtok, tpos);

    gemm_kernel<2, true, true><<<dim3(16, 32, 8), 256, 0, stream>>>(
        xn2b, W1, hb, b1, nullptr, cnt, goff, gtok, TOK, HIDN, DIM);

    gemm_kernel<3, true, false><<<dim3(8, 32, 8), 256, 0, stream>>>(
        hb, W2, eof, b2, nullptr, cnt, goff, nullptr, TOK, DIM, HIDN);

    combine_kernel<<<TOK, 256, 0, stream>>>(x2, eof, wtsp, tpos, out);
    loss_kernel<<<1, 64, 0, stream>>>(me, cnt, out);
}

// Round 2
// 618.096 us; speedup vs baseline: 2.0587x; 2.0587x over previous
//
#include <hip/hip_runtime.h>
#include <stdint.h>

#define TOK   4096
#define DIM   1024
#define NH    16
#define DHD   64
#define NE    8
#define HIDN  2048
#define BATCH 2
#define SEQ   2048
#define BK    64

using floatx4 = __attribute__((ext_vector_type(4))) float;
using bfx8    = __attribute__((ext_vector_type(8))) __bf16;
using shortx8 = __attribute__((ext_vector_type(8))) short;

__device__ __forceinline__ unsigned short f2bf(float f) {
    union { float f; unsigned u; } v; v.f = f;
    unsigned u = v.u;
    u += 0x7fffu + ((u >> 16) & 1u);
    return (unsigned short)(u >> 16);
}

__device__ __forceinline__ floatx4 mfma16(bfx8 a, bfx8 b, floatx4 c) {
    return __builtin_amdgcn_mfma_f32_16x16x32_bf16(a, b, c, 0, 0, 0);
}

__device__ __forceinline__ void gload16(const unsigned short* g, unsigned short* l) {
    __builtin_amdgcn_global_load_lds(
        (const __attribute__((address_space(1))) unsigned int*)g,
        (__attribute__((address_space(3))) unsigned int*)l, 16, 0, 0);
}

// ---------------- f32 -> bf16 straight convert ----------------
__global__ __launch_bounds__(256) void cvt_kernel(const float* __restrict__ in,
                                                  unsigned short* __restrict__ out, int n) {
    int i = (blockIdx.x * 256 + threadIdx.x) * 4;
    if (i < n) {
        float4 v = *reinterpret_cast<const float4*>(in + i);
        out[i + 0] = f2bf(v.x);
        out[i + 1] = f2bf(v.y);
        out[i + 2] = f2bf(v.z);
        out[i + 3] = f2bf(v.w);
    }
}

// ---------------- f32 [R][C] -> bf16 [C][R] transpose-convert (per expert z) ----------------
__global__ __launch_bounds__(256) void transpose_cvt_kernel(const float* __restrict__ in,
                                                            unsigned short* __restrict__ out,
                                                            int R, int C) {
    __shared__ unsigned short t[64][65];
    in  += (size_t)blockIdx.z * R * C;
    out += (size_t)blockIdx.z * R * C;
    int r0 = blockIdx.y * 64, c0 = blockIdx.x * 64;
    int lr = threadIdx.x >> 4, lc = (threadIdx.x & 15) * 4;
#pragma unroll
    for (int p = 0; p < 4; p++) {
        int r = p * 16 + lr;
        float4 v = *reinterpret_cast<const float4*>(in + (size_t)(r0 + r) * C + c0 + lc);
        t[lc + 0][r] = f2bf(v.x);
        t[lc + 1][r] = f2bf(v.y);
        t[lc + 2][r] = f2bf(v.z);
        t[lc + 3][r] = f2bf(v.w);
    }
    __syncthreads();
    int c = threadIdx.x >> 2, ch = (threadIdx.x & 3) * 16;
    shortx8 o0, o1;
#pragma unroll
    for (int q = 0; q < 8; q++) { o0[q] = t[c][ch + q]; o1[q] = t[c][ch + 8 + q]; }
    unsigned short* op = out + (size_t)(c0 + c) * R + r0 + ch;
    *reinterpret_cast<shortx8*>(op) = o0;
    *reinterpret_cast<shortx8*>(op + 8) = o1;
}

// ---------------- layernorm: one block per row ----------------
__global__ __launch_bounds__(256) void ln_kernel(const float* __restrict__ x,
                                                 const float* __restrict__ g,
                                                 const float* __restrict__ b,
                                                 unsigned short* __restrict__ obf) {
    int t = blockIdx.x;
    int tid = threadIdx.x;
    const float* xr = x + (size_t)t * DIM;
    float4 v = *reinterpret_cast<const float4*>(xr + tid * 4);
    float s  = v.x + v.y + v.z + v.w;
    float s2 = v.x * v.x + v.y * v.y + v.z * v.z + v.w * v.w;
    for (int o = 32; o > 0; o >>= 1) {
        s  += __shfl_down(s,  o, 64);
        s2 += __shfl_down(s2, o, 64);
    }
    __shared__ float red[10];
    int lane = tid & 63, w = tid >> 6;
    if (lane == 0) { red[w] = s; red[4 + w] = s2; }
    __syncthreads();
    if (tid == 0) {
        float ts = red[0] + red[1] + red[2] + red[3];
        float t2 = red[4] + red[5] + red[6] + red[7];
        float mu = ts * (1.0f / DIM);
        float var = t2 * (1.0f / DIM) - mu * mu;
        red[8] = mu;
        red[9] = rsqrtf(var + 1e-5f);
    }
    __syncthreads();
    float mu = red[8], rstd = red[9];
    float4 gv = *reinterpret_cast<const float4*>(g + tid * 4);
    float4 bv = *reinterpret_cast<const float4*>(b + tid * 4);
    size_t o = (size_t)t * DIM + tid * 4;
    obf[o + 0] = f2bf((v.x - mu) * rstd * gv.x + bv.x);
    obf[o + 1] = f2bf((v.y - mu) * rstd * gv.y + bv.y);
    obf[o + 2] = f2bf((v.z - mu) * rstd * gv.z + bv.z);
    obf[o + 3] = f2bf((v.w - mu) * rstd * gv.w + bv.w);
}

// ---------------- MFMA GEMM: C = A(bf16 [M][K]) * B^T(bf16 [N][K]) + epilogue ----------------
// EPI: 0 = bias -> bf16 ; 1 = bias + resid -> f32 ; 2 = bias + gelu -> bf16 (row go+r)
//      3 = bias -> f32 (row go+r)
// GATHER: A rows via gtok[go+row]; else if cnt: A row = go+row; else row.
// LDS: linear [128][BK] shorts (128B rows), 16B chunks XOR-swizzled by (row&7);
//      swizzle applied on the GLOBAL source so global_load_lds dest stays linear.
template <int EPI, bool GATHER>
__global__ __launch_bounds__(256) void gemm_kernel(const unsigned short* __restrict__ A,
                                                   const unsigned short* __restrict__ Bt,
                                                   void* __restrict__ C,
                                                   const float* __restrict__ bias,
                                                   const float* __restrict__ resid,
                                                   const int* __restrict__ cnt,
                                                   const int* __restrict__ goff,
                                                   const int* __restrict__ gtok,
                                                   int M, int N, int K) {
    int e = blockIdx.z;
    int Me = cnt ? cnt[e] : M;
    int brow = blockIdx.y * 128;
    if (brow >= Me) return;
    int bcol = blockIdx.x * 128;
    int go = goff ? goff[e] : 0;
    const unsigned short* Be = Bt + (size_t)e * N * K;
    const float* biasp = bias + (size_t)e * N;

    __shared__ unsigned short As[128 * BK];
    __shared__ unsigned short Bs[128 * BK];

    int tid = threadIdx.x, lane = tid & 63, w = tid >> 6;
    int wr = w >> 1, wc = w & 1;
    int cg = lane >> 4, cl = lane & 15;

    // staging source pointers: slot s = w*256 + i*64 + lane (16B units)
    const unsigned short* aga[4];
    const unsigned short* bga[4];
    unsigned short* asb = As + w * 2048;
    unsigned short* bsb = Bs + w * 2048;
#pragma unroll
    for (int i = 0; i < 4; i++) {
        int s = w * 256 + i * 64 + lane;
        int row = s >> 3;
        int c = (s & 7) ^ (row & 7);   // logical 16B chunk within the row
        int gr = brow + row;
        if (gr >= Me) gr = Me - 1;
        long ar;
        if (GATHER) ar = gtok[go + gr];
        else if (cnt) ar = go + gr;
        else ar = gr;
        aga[i] = A + ar * (long)K + c * 8;
        bga[i] = Be + (size_t)(bcol + row) * K + c * 8;
    }

    floatx4 acc[4][4];
#pragma unroll
    for (int m = 0; m < 4; m++)
#pragma unroll
        for (int n = 0; n < 4; n++) acc[m][n] = (floatx4){0.f, 0.f, 0.f, 0.f};

    for (int kt = 0; kt < K; kt += BK) {
#pragma unroll
        for (int i = 0; i < 4; i++) {
            gload16(aga[i], asb + i * 512);
            gload16(bga[i], bsb + i * 512);
            aga[i] += BK;
            bga[i] += BK;
        }
        __syncthreads();
#pragma unroll
        for (int ks = 0; ks < 2; ks++) {
            bfx8 af[4], bf[4];
#pragma unroll
            for (int m = 0; m < 4; m++) {
                int row = wr * 64 + m * 16 + cl;
                af[m] = *reinterpret_cast<const bfx8*>(
                    As + row * BK + (((ks * 4 + cg) ^ (row & 7)) << 3));
            }
#pragma unroll
            for (int n = 0; n < 4; n++) {
                int row = wc * 64 + n * 16 + cl;
                bf[n] = *reinterpret_cast<const bfx8*>(
                    Bs + row * BK + (((ks * 4 + cg) ^ (row & 7)) << 3));
            }
#pragma unroll
            for (int m = 0; m < 4; m++)
#pragma unroll
                for (int n = 0; n < 4; n++) acc[m][n] = mfma16(af[m], bf[n], acc[m][n]);
        }
        __syncthreads();
    }

#pragma unroll
    for (int m = 0; m < 4; m++) {
#pragma unroll
        for (int j = 0; j < 4; j++) {
            int r = brow + wr * 64 + m * 16 + cg * 4 + j;
            if (r >= Me) continue;
#pragma unroll
            for (int n = 0; n < 4; n++) {
                int col = bcol + wc * 64 + n * 16 + cl;
                float v = acc[m][n][j] + biasp[col];
                if (EPI == 0) {
                    ((unsigned short*)C)[(size_t)r * N + col] = f2bf(v);
                } else if (EPI == 1) {
                    size_t o = (size_t)r * N + col;
                    ((float*)C)[o] = v + resid[o];
                } else if (EPI == 2) {
                    float gg = 0.5f * v * (1.0f + erff(v * 0.70710678f));
                    ((unsigned short*)C)[(size_t)(go + r) * N + col] = f2bf(gg);
                } else {
                    ((float*)C)[(size_t)(go + r) * N + col] = v;
                }
            }
        }
    }
}

// ---------------- flash attention ----------------
__global__ __launch_bounds__(256) void attn_kernel(const unsigned short* __restrict__ qkv,
                                                   const unsigned char* __restrict__ mask,
                                                   unsigned short* __restrict__ ao) {
    __shared__ short Ks[32][72];
    __shared__ short Vt[64][40];
    __shared__ short Ps[4][16][40];

    int tid = threadIdx.x, lane = tid & 63, w = tid >> 6;
    int cg = lane >> 4, cl = lane & 15;
    int qb = blockIdx.x * 64, h = blockIdx.y, b = blockIdx.z;

    int tq = qb + w * 16 + cl;
    const unsigned short* qrow = qkv + (size_t)(b * SEQ + tq) * 3 * DIM + h * DHD;
    bfx8 aq0 = *reinterpret_cast<const bfx8*>(qrow + cg * 8);
    bfx8 aq1 = *reinterpret_cast<const bfx8*>(qrow + 32 + cg * 8);

    floatx4 accO[4];
#pragma unroll
    for (int d = 0; d < 4; d++) accO[d] = (floatx4){0.f, 0.f, 0.f, 0.f};
    float m0[4], l0[4];
#pragma unroll
    for (int j = 0; j < 4; j++) { m0[j] = -3.0e38f; l0[j] = 0.f; }

    for (int kt = 0; kt < SEQ; kt += 32) {
        {
            int r = tid >> 3, c8 = (tid & 7) * 8;
            const unsigned short* trow = qkv + (size_t)(b * SEQ + kt + r) * 3 * DIM + h * DHD;
            shortx8 kvv = *reinterpret_cast<const shortx8*>(trow + DIM + c8);
            *reinterpret_cast<shortx8*>(&Ks[r][c8]) = kvv;
            shortx8 vv = *reinterpret_cast<const shortx8*>(trow + 2 * DIM + c8);
#pragma unroll
            for (int e2 = 0; e2 < 8; e2++) Vt[c8 + e2][r] = vv[e2];
        }
        __syncthreads();

        floatx4 accS[2];
        accS[0] = (floatx4){0.f, 0.f, 0.f, 0.f};
        accS[1] = (floatx4){0.f, 0.f, 0.f, 0.f};
#pragma unroll
        for (int nt = 0; nt < 2; nt++) {
            bfx8 bk0 = *reinterpret_cast<const bfx8*>(&Ks[nt * 16 + cl][cg * 8]);
            bfx8 bk1 = *reinterpret_cast<const bfx8*>(&Ks[nt * 16 + cl][32 + cg * 8]);
            accS[nt] = mfma16(aq0, bk0, accS[nt]);
            accS[nt] = mfma16(aq1, bk1, accS[nt]);
        }

        float mk0 = mask[b * SEQ + kt + cl]      ? -1e9f : 0.f;
        float mk1 = mask[b * SEQ + kt + 16 + cl] ? -1e9f : 0.f;
        float s0[4], s1[4], pm[4];
#pragma unroll
        for (int j = 0; j < 4; j++) {
            s0[j] = accS[0][j] * 0.125f + mk0;
            s1[j] = accS[1][j] * 0.125f + mk1;
            pm[j] = fmaxf(s0[j], s1[j]);
        }
        for (int o = 1; o < 16; o <<= 1)
#pragma unroll
            for (int j = 0; j < 4; j++) pm[j] = fmaxf(pm[j], __shfl_xor(pm[j], o, 16));
        float al[4], rs[4];
#pragma unroll
        for (int j = 0; j < 4; j++) {
            float mn = fmaxf(m0[j], pm[j]);
            al[j] = __expf(m0[j] - mn);
            m0[j] = mn;
            s0[j] = __expf(s0[j] - mn);
            s1[j] = __expf(s1[j] - mn);
            rs[j] = s0[j] + s1[j];
        }
        for (int o = 1; o < 16; o <<= 1)
#pragma unroll
            for (int j = 0; j < 4; j++) rs[j] += __shfl_xor(rs[j], o, 16);
#pragma unroll
        for (int j = 0; j < 4; j++) l0[j] = l0[j] * al[j] + rs[j];
#pragma unroll
        for (int d = 0; d < 4; d++)
#pragma unroll
            for (int j = 0; j < 4; j++) accO[d][j] *= al[j];

#pragma unroll
        for (int j = 0; j < 4; j++) {
            Ps[w][cg * 4 + j][cl]      = (short)f2bf(s0[j]);
            Ps[w][cg * 4 + j][16 + cl] = (short)f2bf(s1[j]);
        }
        bfx8 pa = *reinterpret_cast<const bfx8*>(&Ps[w][cl][cg * 8]);
#pragma unroll
        for (int d = 0; d < 4; d++) {
            bfx8 bv = *reinterpret_cast<const bfx8*>(&Vt[d * 16 + cl][cg * 8]);
            accO[d] = mfma16(pa, bv, accO[d]);
        }
        __syncthreads();
    }

#pragma unroll
    for (int d = 0; d < 4; d++)
#pragma unroll
        for (int j = 0; j < 4; j++) {
            size_t row = (size_t)(b * SEQ + qb + w * 16 + cg * 4 + j);
            ao[row * DIM + h * DHD + d * 16 + cl] = f2bf(accO[d][j] / l0[j]);
        }
}

// ---------------- gating with fused LN2: one wave per token ----------------
__global__ __launch_bounds__(256) void gate_kernel(const float* __restrict__ x2,
                                                   const float* __restrict__ lng,
                                                   const float* __restrict__ lnb,
                                                   const float* __restrict__ Wg,
                                                   const float* __restrict__ bg,
                                                   int* __restrict__ idx,
                                                   float* __restrict__ wts,
                                                   int* __restrict__ cnt,
                                                   float* __restrict__ me_sum) {
    __shared__ float bme[8];
    if (threadIdx.x < 8) bme[threadIdx.x] = 0.f;
    __syncthreads();
    int w = threadIdx.x >> 6, lane = threadIdx.x & 63;
    int t = blockIdx.x * 4 + w;
    const float* xr = x2 + (size_t)t * DIM;
    float xv[16];
    float s = 0.f, s2 = 0.f;
#pragma unroll
    for (int k = 0; k < 16; k++) {
        float x = xr[lane + 64 * k];
        xv[k] = x; s += x; s2 += x * x;
    }
    for (int o = 32; o > 0; o >>= 1) {
        s  += __shfl_xor(s,  o, 64);
        s2 += __shfl_xor(s2, o, 64);
    }
    float mu = s * (1.0f / DIM);
    float rstd = rsqrtf(s2 * (1.0f / DIM) - mu * mu + 1e-5f);
    float acc[8];
#pragma unroll
    for (int e = 0; e < 8; e++) acc[e] = 0.f;
#pragma unroll
    for (int k = 0; k < 16; k++) {
        int d = lane + 64 * k;
        float xn = (xv[k] - mu) * rstd * lng[d] + lnb[d];
        const float* wr = Wg + d * 8;
#pragma unroll
        for (int e = 0; e < 8; e++) acc[e] += xn * wr[e];
    }
    for (int o = 32; o > 0; o >>= 1)
#pragma unroll
        for (int e = 0; e < 8; e++) acc[e] += __shfl_xor(acc[e], o, 64);
    if (lane == 0) {
        float p[8];
        float mx = -3e38f;
#pragma unroll
        for (int e = 0; e < 8; e++) { acc[e] += bg[e]; mx = fmaxf(mx, acc[e]); }
        float se = 0.f;
#pragma unroll
        for (int e = 0; e < 8; e++) { p[e] = expf(acc[e] - mx); se += p[e]; }
#pragma unroll
        for (int e = 0; e < 8; e++) p[e] /= se;
        int i0 = 0; float v0 = p[0];
#pragma unroll
        for (int e = 1; e < 8; e++) if (p[e] > v0) { v0 = p[e]; i0 = e; }
        int i1 = -1; float v1 = -3e38f;
#pragma unroll
        for (int e = 0; e < 8; e++) if (e != i0 && p[e] > v1) { v1 = p[e]; i1 = e; }
        float sw = v0 + v1;
        idx[t * 2]     = i0;
        idx[t * 2 + 1] = i1;
        wts[t * 2]     = v0 / sw;
        wts[t * 2 + 1] = v1 / sw;
        atomicAdd(&cnt[i0], 1);
        atomicAdd(&cnt[i1], 1);
#pragma unroll
        for (int e = 0; e < 8; e++) atomicAdd(&bme[e], p[e]);
    }
    __syncthreads();
    if (threadIdx.x < 8) atomicAdd(&me_sum[threadIdx.x], bme[threadIdx.x]);
}

__global__ void prefix_kernel(const int* __restrict__ cnt, int* __restrict__ goff) {
    if (threadIdx.x == 0) {
        int s = 0;
        for (int e = 0; e < 8; e++) { goff[e] = s; s += cnt[e]; }
        goff[8] = s;
    }
}

__global__ __launch_bounds__(256) void assign_kernel(const int* __restrict__ idx,
                                                     const int* __restrict__ goff,
                                                     int* __restrict__ fill,
                                                     int* __restrict__ gtok,
                                                     int* __restrict__ tpos) {
    int t = blockIdx.x * 256 + threadIdx.x;
    for (int j = 0; j < 2; j++) {
        int e = idx[t * 2 + j];
        int pos = goff[e] + atomicAdd(&fill[e], 1);
        gtok[pos] = t;
        tpos[t * 2 + j] = pos;
    }
}

__global__ __launch_bounds__(256) void combine_kernel(const float* __restrict__ x2,
                                                      const float* __restrict__ eo,
                                                      const float* __restrict__ wts,
                                                      const int* __restrict__ tpos,
                                                      float* __restrict__ out) {
    int t = blockIdx.x;
    int c = threadIdx.x * 4;
    float w0 = wts[t * 2], w1 = wts[t * 2 + 1];
    int p0 = tpos[t * 2], p1 = tpos[t * 2 + 1];
    float4 r  = *reinterpret_cast<const float4*>(x2 + (size_t)t * DIM + c);
    float4 a  = *reinterpret_cast<const float4*>(eo + (size_t)p0 * DIM + c);
    float4 bb = *reinterpret_cast<const float4*>(eo + (size_t)p1 * DIM + c);
    float4 o;
    o.x = r.x + w0 * a.x + w1 * bb.x;
    o.y = r.y + w0 * a.y + w1 * bb.y;
    o.z = r.z + w0 * a.z + w1 * bb.z;
    o.w = r.w + w0 * a.w + w1 * bb.w;
    *reinterpret_cast<float4*>(out + (size_t)t * DIM + c) = o;
}

__global__ void loss_kernel(const float* __restrict__ me_sum, const int* __restrict__ cnt,
                            float* __restrict__ out) {
    if (threadIdx.x == 0 && blockIdx.x == 0) {
        float s = 0.f;
        for (int e = 0; e < 8; e++)
            s += (me_sum[e] / 4096.0f) * ((float)cnt[e] / 4096.0f);
        out[(size_t)TOK * DIM] = 8.0f * s;
    }
}

extern "C" void kernel_launch(void* const* d_in, const int* in_sizes, int n_in,
                              void* d_out, int out_size, void* d_ws, size_t ws_size,
                              hipStream_t stream) {
    const float* x    = (const float*)d_in[0];
    const unsigned char* mask = (const unsigned char*)d_in[1];
    const float* ln1g = (const float*)d_in[2];
    const float* ln1b = (const float*)d_in[3];
    const float* Wqkv = (const float*)d_in[4];
    const float* bqkv = (const float*)d_in[5];
    const float* Wo   = (const float*)d_in[6];
    const float* bo   = (const float*)d_in[7];
    const float* ln2g = (const float*)d_in[8];
    const float* ln2b = (const float*)d_in[9];
    const float* Wg   = (const float*)d_in[10];
    const float* bg   = (const float*)d_in[11];
    const float* W1   = (const float*)d_in[12];
    const float* b1   = (const float*)d_in[13];
    const float* W2   = (const float*)d_in[14];
    const float* b2   = (const float*)d_in[15];
    float* out = (float*)d_out;

    char* ws = (char*)d_ws;
    int*   cnt  = (int*)(ws + 0);
    int*   fill = (int*)(ws + 64);
    int*   goff = (int*)(ws + 128);
    float* me   = (float*)(ws + 192);
    size_t off = 1024;
    auto alloc = [&](size_t bytes) -> void* {
        void* p = ws + off;
        off += (bytes + 255) & ~(size_t)255;
        return p;
    };
    const size_t SZ_QKVB = (size_t)TOK * 3 * DIM * 2;      // 25.2 MB
    const size_t SZ_HB   = (size_t)2 * TOK * HIDN * 2;     // 33.6 MB
    const size_t SZ_EOF  = (size_t)2 * TOK * DIM * 4;      // 33.6 MB
    // Region 1: qkvb (phase A) then hb (phase B)
    char* R1 = (char*)alloc(SZ_HB > SZ_QKVB ? SZ_HB : SZ_QKVB);
    // Region 2: xn1|aob|wqkvb|wob (phase A) then eof (phase B)
    char* R2 = (char*)alloc(SZ_EOF);
    unsigned short* qkvb  = (unsigned short*)R1;
    unsigned short* hb    = (unsigned short*)R1;
    float*          eof   = (float*)R2;
    unsigned short* xn1   = (unsigned short*)R2;                               // 8.4 MB
    unsigned short* aob   = (unsigned short*)(R2 + (size_t)TOK * DIM * 2);     // 8.4 MB
    unsigned short* wqkvb = (unsigned short*)(R2 + (size_t)2 * TOK * DIM * 2); // 6.3 MB
    unsigned short* wob   = (unsigned short*)(R2 + (size_t)2 * TOK * DIM * 2 +
                                              (size_t)3 * DIM * DIM * 2);      // 2.1 MB
    float*          x2    = (float*)alloc((size_t)TOK * DIM * 4);
    unsigned short* xn2b  = (unsigned short*)alloc((size_t)TOK * DIM * 2);
    unsigned short* w1t   = (unsigned short*)alloc((size_t)NE * DIM * HIDN * 2);
    unsigned short* w2t   = (unsigned short*)alloc((size_t)NE * DIM * HIDN * 2);
    int*            idxp  = (int*)alloc((size_t)TOK * 2 * 4);
    float*          wtsp  = (float*)alloc((size_t)TOK * 2 * 4);
    int*            gtok  = (int*)alloc((size_t)2 * TOK * 4);
    int*            tpos  = (int*)alloc((size_t)TOK * 2 * 4);

    hipMemsetAsync(ws, 0, 256, stream);

    // weight prep: straight converts + per-expert transposes to bf16 [N][K]
    cvt_kernel<<<3 * DIM * DIM / 1024, 256, 0, stream>>>(Wqkv, wqkvb, 3 * DIM * DIM);
    cvt_kernel<<<DIM * DIM / 1024, 256, 0, stream>>>(Wo, wob, DIM * DIM);
    transpose_cvt_kernel<<<dim3(HIDN / 64, DIM / 64, NE), 256, 0, stream>>>(W1, w1t, DIM, HIDN);
    transpose_cvt_kernel<<<dim3(DIM / 64, HIDN / 64, NE), 256, 0, stream>>>(W2, w2t, HIDN, DIM);

    ln_kernel<<<TOK, 256, 0, stream>>>(x, ln1g, ln1b, xn1);

    gemm_kernel<0, false><<<dim3(24, 32, 1), 256, 0, stream>>>(
        xn1, wqkvb, qkvb, bqkv, nullptr, nullptr, nullptr, nullptr, TOK, 3 * DIM, DIM);

    attn_kernel<<<dim3(SEQ / 64, NH, BATCH), 256, 0, stream>>>(qkvb, mask, aob);

    gemm_kernel<1, false><<<dim3(8, 32, 1), 256, 0, stream>>>(
        aob, wob, x2, bo, x, nullptr, nullptr, nullptr, TOK, DIM, DIM);

    ln_kernel<<<TOK, 256, 0, stream>>>(x2, ln2g, ln2b, xn2b);

    gate_kernel<<<TOK / 4, 256, 0, stream>>>(x2, ln2g, ln2b, Wg, bg, idxp, wtsp, cnt, me);
    prefix_kernel<<<1, 64, 0, stream>>>(cnt, goff);
    assign_kernel<<<TOK / 256, 256, 0, stream>>>(idxp, goff, fill, gtok, tpos);

    gemm_kernel<2, true><<<dim3(16, 16, 8), 256, 0, stream>>>(
        xn2b, w1t, hb, b1, nullptr, cnt, goff, gtok, TOK, HIDN, DIM);

    gemm_kernel<3, false><<<dim3(8, 16, 8), 256, 0, stream>>>(
        hb, w2t, eof, b2, nullptr, cnt, goff, nullptr, TOK, DIM, HIDN);

    combine_kernel<<<TOK, 256, 0, stream>>>(x2, eof, wtsp, tpos, out);
    loss_kernel<<<1, 64, 0, stream>>>(me, cnt, out);
}